// Round 1
// 605.906 us; speedup vs baseline: 1.1602x; 1.1602x over previous
//
#include <hip/hip_runtime.h>
#include <hip/hip_bf16.h>
#include <cstdint>
#include <cstddef>

// Problem constants
#define K_DIM   4096          // INF
#define N_DIM   11008         // OUTF
#define M_DIM   4096          // 2*2048
#define GROUPS  32
#define QROWS   512           // INF*4/32

typedef __bf16 bf16x8 __attribute__((ext_vector_type(8)));
typedef float  f32x4  __attribute__((ext_vector_type(4)));

// ---------------------------------------------------------------------------
// async 16B global -> LDS (wave-uniform LDS base + lane*16 semantics)
// ---------------------------------------------------------------------------
__device__ __forceinline__ void async16(const void* g, void* lds) {
    __builtin_amdgcn_global_load_lds(
        (const __attribute__((address_space(1))) uint32_t*)g,
        (__attribute__((address_space(3))) uint32_t*)lds,
        16, 0, 0);
}

#define FENCE() asm volatile("" ::: "memory")
#define BAR()   do { FENCE(); __builtin_amdgcn_s_barrier(); FENCE(); } while (0)

// ---------------------------------------------------------------------------
// Kernel 1: dequantize packed 4-bit weights into B^T bf16 layout (N x K).
// (unchanged from baseline — revisit with counters once GEMM no longer dominates)
// ---------------------------------------------------------------------------
#define DQ_NN   64
#define DQ_KK   32
#define DQ_ROW  264   // 256 k-elements + 8 pad (16B) -> 528B row stride
__global__ __launch_bounds__(256) void dequant_kernel(
        const uint32_t* __restrict__ qw,
        const float* __restrict__ scales,
        const float* __restrict__ zeros,
        __bf16* __restrict__ Wt) {
    __shared__ __align__(16) __bf16 T[DQ_NN * DQ_ROW];   // 33,792 B

    const int n0  = blockIdx.x * DQ_NN;
    const int kk0 = blockIdx.y * DQ_KK;
    const int tid = threadIdx.x;

#pragma unroll
    for (int it = 0; it < 8; ++it) {
        const int flat = it * 256 + tid;
        const int kk_l = flat >> 6;          // 0..31
        const int n_l  = flat & 63;          // 0..63
        const int kk   = kk0 + kk_l;
        const int n    = n0 + n_l;
        const uint32_t q = qw[(size_t)kk * N_DIM + n];
        const int g = kk >> 4;               // k-group = (kk*8)/128
        const float s = scales[(size_t)n * GROUPS + g];
        const float z = zeros[(size_t)n * GROUPS + g];
        bf16x8 w;
#pragma unroll
        for (int j = 0; j < 8; ++j) {
            float v = (float)((q >> (4 * j)) & 0xF) * s - z;
            w[j] = (__bf16)v;
        }
        *(bf16x8*)(&T[n_l * DQ_ROW + kk_l * 8]) = w;
    }
    __syncthreads();

#pragma unroll
    for (int it = 0; it < 8; ++it) {
        const int flat = it * 256 + tid;
        const int n_l    = flat >> 5;        // 0..63
        const int kchunk = flat & 31;        // 0..31 (8 elems each)
        bf16x8 v = *(const bf16x8*)(&T[n_l * DQ_ROW + kchunk * 8]);
        *(bf16x8*)(Wt + (size_t)(n0 + n_l) * K_DIM + (size_t)kk0 * 8 + kchunk * 8) = v;
    }
}

// ---------------------------------------------------------------------------
// Kernel 2: x fp32 -> bf16 (RNE), 8 elements per thread (unchanged)
// ---------------------------------------------------------------------------
__global__ __launch_bounds__(256) void xconv_kernel(
        const float* __restrict__ x, __bf16* __restrict__ xb) {
    const size_t i = ((size_t)blockIdx.x * 256 + threadIdx.x) * 8;
    const float4* p = (const float4*)(x + i);
    float4 a = p[0];
    float4 b = p[1];
    bf16x8 o;
    o[0] = (__bf16)a.x; o[1] = (__bf16)a.y; o[2] = (__bf16)a.z; o[3] = (__bf16)a.w;
    o[4] = (__bf16)b.x; o[5] = (__bf16)b.y; o[6] = (__bf16)b.z; o[7] = (__bf16)b.w;
    *(bf16x8*)(xb + i) = o;
}

// ---------------------------------------------------------------------------
// Kernel 3: bf16 GEMM, C = A(M x K) * Bt(N x K)^T + bias, fp32 out.
//
// 256x256 tile, BK=64, 512 threads = 8 waves (2M x 4N), per-wave 128x64
// output = acc[8][4] f32x4.  4-phase-per-K-tile schedule (the verified
// 8-phase/2-tile template): counted vmcnt across barriers (never 0 in
// steady state), setprio(1) around MFMA clusters, XOR-8 LDS swizzle with
// pre-swizzled global source (global_load_lds writes linearly).
//
// LDS (128 KiB): A0[0) A1[32KB) B0[64KB) B1[96KB), each buffer [256][64]
// bf16, row = 128 B = 8 x 16B chunks.  Chunk swizzle: logical col-chunk c
// of row r stored at physical chunk c ^ (r&7).  Staging instr j covers one
// 64-row quarter (8 KB = 512 thr x 16 B); thread t sources global element
// (row0 + (t>>3), ((t&7) ^ ((t>>3)&7))*8 + ktile).
//
// Staging issue order per group (tile g+1 -> other buffer):
//   p0: Aq0,Aq2 | p1: Bq0,Bq1 | p2: Bq2,Bq3 | p3: Aq1,Aq3
// Phase p reads (tile g):  p: mf = {2p,2p+1} x nf 0..3 x ks 0,1 (16 MFMA).
//   p0 needs Aq0,Aq2,Bq0-3 (staged prev p0-p2)  -> vmcnt(2) allows prev p3
//   p2 needs Aq1,Aq3       (staged prev p3)     -> vmcnt(4) allows cur p0,p1
// Min prefetch lead = 2 phases; last group uses vmcnt(0).
// ---------------------------------------------------------------------------
#define BM 256
#define BN 256
#define BK 64
#define NT 43            // N_DIM/256
#define MT 16            // M_DIM/256
#define NWG (NT*MT)      // 688 = 8*86 -> bijective XCD swizzle

// 16-MFMA phase body: A-frag loads, 2 staging issues, mid-barrier, MFMA.
// b?k? fragment registers are in enclosing kgroup scope (loaded in phase 0).
#define PH_BODY(MF, J0, J1)                                                   \
    do {                                                                      \
        bf16x8 aLk0 = *(const bf16x8*)(ar0 + (MF)*1024);                      \
        bf16x8 aLk1 = *(const bf16x8*)(ar1 + (MF)*1024);                      \
        bf16x8 aHk0 = *(const bf16x8*)(ar0 + ((MF)+1)*1024);                  \
        bf16x8 aHk1 = *(const bf16x8*)(ar1 + ((MF)+1)*1024);                  \
        if constexpr (DO_STAGE) {                                             \
            async16(gsrc[(J0)], lds + ldst[(J0)] + soff);                     \
            async16(gsrc[(J1)], lds + ldst[(J1)] + soff);                     \
        }                                                                     \
        BAR();                                                                \
        __builtin_amdgcn_s_setprio(1);                                        \
        acc[(MF)  ][0] = __builtin_amdgcn_mfma_f32_16x16x32_bf16(aLk0, b0k0, acc[(MF)  ][0], 0,0,0); \
        acc[(MF)  ][1] = __builtin_amdgcn_mfma_f32_16x16x32_bf16(aLk0, b1k0, acc[(MF)  ][1], 0,0,0); \
        acc[(MF)  ][2] = __builtin_amdgcn_mfma_f32_16x16x32_bf16(aLk0, b2k0, acc[(MF)  ][2], 0,0,0); \
        acc[(MF)  ][3] = __builtin_amdgcn_mfma_f32_16x16x32_bf16(aLk0, b3k0, acc[(MF)  ][3], 0,0,0); \
        acc[(MF)+1][0] = __builtin_amdgcn_mfma_f32_16x16x32_bf16(aHk0, b0k0, acc[(MF)+1][0], 0,0,0); \
        acc[(MF)+1][1] = __builtin_amdgcn_mfma_f32_16x16x32_bf16(aHk0, b1k0, acc[(MF)+1][1], 0,0,0); \
        acc[(MF)+1][2] = __builtin_amdgcn_mfma_f32_16x16x32_bf16(aHk0, b2k0, acc[(MF)+1][2], 0,0,0); \
        acc[(MF)+1][3] = __builtin_amdgcn_mfma_f32_16x16x32_bf16(aHk0, b3k0, acc[(MF)+1][3], 0,0,0); \
        acc[(MF)  ][0] = __builtin_amdgcn_mfma_f32_16x16x32_bf16(aLk1, b0k1, acc[(MF)  ][0], 0,0,0); \
        acc[(MF)  ][1] = __builtin_amdgcn_mfma_f32_16x16x32_bf16(aLk1, b1k1, acc[(MF)  ][1], 0,0,0); \
        acc[(MF)  ][2] = __builtin_amdgcn_mfma_f32_16x16x32_bf16(aLk1, b2k1, acc[(MF)  ][2], 0,0,0); \
        acc[(MF)  ][3] = __builtin_amdgcn_mfma_f32_16x16x32_bf16(aLk1, b3k1, acc[(MF)  ][3], 0,0,0); \
        acc[(MF)+1][0] = __builtin_amdgcn_mfma_f32_16x16x32_bf16(aHk1, b0k1, acc[(MF)+1][0], 0,0,0); \
        acc[(MF)+1][1] = __builtin_amdgcn_mfma_f32_16x16x32_bf16(aHk1, b1k1, acc[(MF)+1][1], 0,0,0); \
        acc[(MF)+1][2] = __builtin_amdgcn_mfma_f32_16x16x32_bf16(aHk1, b2k1, acc[(MF)+1][2], 0,0,0); \
        acc[(MF)+1][3] = __builtin_amdgcn_mfma_f32_16x16x32_bf16(aHk1, b3k1, acc[(MF)+1][3], 0,0,0); \
        __builtin_amdgcn_s_setprio(0);                                        \
    } while (0)

// One K-tile (4 phases). ar0/ar1,br0/br1 = this buffer's per-lane ds_read
// bases (ks0/ks1 swizzled cols). soff = staging buffer offset (elements).
template<bool DO_STAGE>
__device__ __forceinline__ void kgroup(
        const __bf16* __restrict__ ar0, const __bf16* __restrict__ ar1,
        const __bf16* __restrict__ br0, const __bf16* __restrict__ br1,
        const __bf16* (&gsrc)[8], __bf16* lds, const int (&ldst)[8],
        const int soff, f32x4 (&acc)[8][4])
{
    // ---- phase 0 : mf 0,1 (fresh Aq0/Aq2 + all B) ----
    asm volatile("s_waitcnt vmcnt(2)" ::: "memory");
    BAR();
    bf16x8 b0k0 = *(const bf16x8*)(br0 + 0*1024);
    bf16x8 b1k0 = *(const bf16x8*)(br0 + 1*1024);
    bf16x8 b2k0 = *(const bf16x8*)(br0 + 2*1024);
    bf16x8 b3k0 = *(const bf16x8*)(br0 + 3*1024);
    bf16x8 b0k1 = *(const bf16x8*)(br1 + 0*1024);
    bf16x8 b1k1 = *(const bf16x8*)(br1 + 1*1024);
    bf16x8 b2k1 = *(const bf16x8*)(br1 + 2*1024);
    bf16x8 b3k1 = *(const bf16x8*)(br1 + 3*1024);
    PH_BODY(0, 0, 1);
    // ---- phase 1 : mf 2,3 ----
    BAR();
    PH_BODY(2, 2, 3);
    // ---- phase 2 : mf 4,5 (fresh Aq1/Aq3) ----
    if constexpr (DO_STAGE) { asm volatile("s_waitcnt vmcnt(4)" ::: "memory"); }
    else                    { asm volatile("s_waitcnt vmcnt(0)" ::: "memory"); }
    BAR();
    PH_BODY(4, 4, 5);
    // ---- phase 3 : mf 6,7 ----
    BAR();
    PH_BODY(6, 6, 7);
    if constexpr (DO_STAGE) {
#pragma unroll
        for (int j = 0; j < 8; ++j) gsrc[j] += BK;
    }
}

__global__ __launch_bounds__(512, 2) void gemm_kernel(
        const __bf16* __restrict__ A,    // M x K row-major (bf16 x)
        const __bf16* __restrict__ Bt,   // N x K row-major (dequant W^T)
        const float* __restrict__ bias,  // N
        float* __restrict__ C) {         // M x N row-major
    __shared__ __align__(16) __bf16 lds[65536];   // 128 KiB

    const int tid  = threadIdx.x;
    const int wave = tid >> 6;
    const int lane = tid & 63;
    const int wm   = wave >> 2;      // 0..1
    const int wn   = wave & 3;       // 0..3
    const int quad = lane >> 4;      // 0..3
    const int l16  = lane & 15;

    // bijective XCD swizzle (688 % 8 == 0), m inner for B-panel L2 reuse
    const int bid = blockIdx.x;
    const int swz = (bid & 7) * (NWG / 8) + (bid >> 3);
    const int n_t = swz >> 4;        // 0..42
    const int m_t = swz & 15;        // 0..15
    const int m0 = m_t << 8;
    const int n0 = n_t << 8;

    f32x4 acc[8][4] = {};

    // ---- staging source (pre-swizzled global addresses, rule 21) ----
    const int srow = tid >> 3;                       // 0..63 row within quarter
    const int scol = ((tid & 7) ^ (srow & 7)) << 3;  // swizzled k-chunk * 8

    // issue order: Aq0, Aq2, Bq0, Bq1, Bq2, Bq3, Aq1, Aq3
    const __bf16* gsrc[8];
    gsrc[0] = A  + (size_t)(m0 +   0 + srow) * K_DIM + scol;
    gsrc[1] = A  + (size_t)(m0 + 128 + srow) * K_DIM + scol;
    gsrc[2] = Bt + (size_t)(n0 +   0 + srow) * K_DIM + scol;
    gsrc[3] = Bt + (size_t)(n0 +  64 + srow) * K_DIM + scol;
    gsrc[4] = Bt + (size_t)(n0 + 128 + srow) * K_DIM + scol;
    gsrc[5] = Bt + (size_t)(n0 + 192 + srow) * K_DIM + scol;
    gsrc[6] = A  + (size_t)(m0 +  64 + srow) * K_DIM + scol;
    gsrc[7] = A  + (size_t)(m0 + 192 + srow) * K_DIM + scol;

    // wave-uniform LDS dest (elements): quarter base + wave*512 (HW adds lane*16B)
    const int wq = wave << 9;
    const int ldst[8] = {
        0*4096 + wq,          2*4096 + wq,
        32768 + 0*4096 + wq,  32768 + 1*4096 + wq,
        32768 + 2*4096 + wq,  32768 + 3*4096 + wq,
        1*4096 + wq,          3*4096 + wq
    };

    // prologue: tile 0 -> buf0 (same issue order as steady state)
#pragma unroll
    for (int j = 0; j < 8; ++j) async16(gsrc[j], lds + ldst[j]);
#pragma unroll
    for (int j = 0; j < 8; ++j) gsrc[j] += BK;

    // ---- compute-side ds_read bases (swizzled cols; row&7 == l16&7) ----
    const int h3  = l16 & 7;
    const int cc0 = (quad ^ h3) << 3;          // ks0 col (elements)
    const int cc1 = ((quad ^ h3) ^ 4) << 3;    // ks1 col = cc0 XOR 32 elems
    const int arow = (wm << 7) + l16;          // + mf*16 via imm offset
    const int brow = (wn << 6) + l16;          // + nf*16 via imm offset

    const __bf16* a00 = lds + arow * 64 + cc0;          // buf0 A ks0
    const __bf16* a01 = lds + arow * 64 + cc1;          // buf0 A ks1
    const __bf16* b00 = lds + 32768 + brow * 64 + cc0;  // buf0 B ks0
    const __bf16* b01 = lds + 32768 + brow * 64 + cc1;  // buf0 B ks1

    // 64 K-tiles: groups alternate buf0/buf1; group g stages tile g+1.
#pragma unroll 1
    for (int gg = 0; gg < 31; ++gg) {
        kgroup<true>(a00,         a01,         b00,         b01,
                     gsrc, lds, ldst, 16384, acc);
        kgroup<true>(a00 + 16384, a01 + 16384, b00 + 16384, b01 + 16384,
                     gsrc, lds, ldst, 0,     acc);
    }
    kgroup<true >(a00,         a01,         b00,         b01,
                  gsrc, lds, ldst, 16384, acc);   // g=62 stages tile 63
    kgroup<false>(a00 + 16384, a01 + 16384, b00 + 16384, b01 + 16384,
                  gsrc, lds, ldst, 0,     acc);   // g=63, vmcnt(0) drain

    // ---- epilogue: C[m][n] = acc + bias[n]; C/D: col=l16, row=quad*4+r ----
#pragma unroll
    for (int nf = 0; nf < 4; ++nf) {
        const int n = n0 + (wn << 6) + (nf << 4) + l16;
        const float bv = bias[n];
#pragma unroll
        for (int mf = 0; mf < 8; ++mf) {
            const int mrow = m0 + (wm << 7) + (mf << 4) + (quad << 2);
            float* cp = C + (size_t)mrow * N_DIM + n;
#pragma unroll
            for (int r = 0; r < 4; ++r)
                cp[(size_t)r * N_DIM] = acc[mf][nf][r] + bv;
        }
    }
}

// ---------------------------------------------------------------------------
extern "C" void kernel_launch(void* const* d_in, const int* in_sizes, int n_in,
                              void* d_out, int out_size, void* d_ws, size_t ws_size,
                              hipStream_t stream) {
    const float*    x      = (const float*)d_in[0];
    const uint32_t* qw     = (const uint32_t*)d_in[1];
    const float*    scales = (const float*)d_in[2];
    const float*    zeros  = (const float*)d_in[3];
    const float*    bias   = (const float*)d_in[4];
    float*          out    = (float*)d_out;

    // workspace layout: Wt (N*K bf16 = 90,177,536 B) | xb (M*K bf16 = 33,554,432 B)
    __bf16* Wt = (__bf16*)d_ws;
    __bf16* xb = (__bf16*)((char*)d_ws + (size_t)N_DIM * K_DIM * sizeof(__bf16));

    dim3 dq_grid(N_DIM / DQ_NN, QROWS / DQ_KK);   // 172 x 16
    dequant_kernel<<<dq_grid, 256, 0, stream>>>(qw, scales, zeros, Wt);
    xconv_kernel<<<(M_DIM * K_DIM) / (256 * 8), 256, 0, stream>>>(x, xb);

    gemm_kernel<<<NWG, 512, 0, stream>>>(xb, Wt, bias, out);
}